// Round 2
// baseline (1848.829 us; speedup 1.0000x reference)
//
#include <hip/hip_runtime.h>
#include <stdint.h>

#define BATCH 8192
#define IN 4096
#define OUT 4096
#define EPS 1e-4f
#define KW 64              // u64 words per row (4096 bits)
#define RCHUNK 128         // rows per partial-sum block
#define NCHUNKS (BATCH / RCHUNK)   // 64

typedef unsigned long long u64;

// ---------------- Kernel 1: partial column sums (S1, S2), float4 ----------------
__global__ __launch_bounds__(256) void colstat_partial(
    const float* __restrict__ x, float* __restrict__ P1, float* __restrict__ P2) {
    int c4 = blockIdx.x * 256 + threadIdx.x;      // float4 column group
    int r0 = blockIdx.y * RCHUNK;
    float4 s1 = make_float4(0.f, 0.f, 0.f, 0.f);
    float4 s2 = make_float4(0.f, 0.f, 0.f, 0.f);
    const float4* p = (const float4*)x + (size_t)r0 * (IN / 4) + c4;
#pragma unroll 4
    for (int r = 0; r < RCHUNK; ++r) {
        float4 v = p[(size_t)r * (IN / 4)];
        s1.x += v.x; s1.y += v.y; s1.z += v.z; s1.w += v.w;
        s2.x += v.x * v.x; s2.y += v.y * v.y; s2.z += v.z * v.z; s2.w += v.w * v.w;
    }
    ((float4*)P1)[blockIdx.y * (IN / 4) + c4] = s1;
    ((float4*)P2)[blockIdx.y * (IN / 4) + c4] = s2;
}

// ---------------- Kernel 2: finalize -> threshold + sign ----------------
// xn>0  <=>  (x - thr)*sgn > 0, thr = mu - beta/a, a = rstd*gamma
__global__ __launch_bounds__(256) void colstat_final(
    const float* __restrict__ P1, const float* __restrict__ P2,
    const float* __restrict__ gamma, const float* __restrict__ beta,
    float* __restrict__ thr, float* __restrict__ sgn) {
    int col = blockIdx.x * 256 + threadIdx.x;
    double s1 = 0.0, s2 = 0.0;
#pragma unroll 8
    for (int c = 0; c < NCHUNKS; ++c) {
        s1 += (double)P1[c * IN + col];
        s2 += (double)P2[c * IN + col];
    }
    double m = s1 / (double)BATCH;
    double var = s2 / (double)BATCH - m * m;
    float a = (float)(1.0 / sqrt(var + (double)EPS)) * gamma[col];
    thr[col] = (float)m - beta[col] / a;
    sgn[col] = (a >= 0.f) ? 1.f : -1.f;
}

// ---------------- Kernel 3: binarize + bit-pack x ----------------
__global__ __launch_bounds__(256) void binx(
    const float* __restrict__ x, const float* __restrict__ thr,
    const float* __restrict__ sgn, u64* __restrict__ xbits) {
    int r = blockIdx.x;
    int tid = threadIdx.x;
    int lane = tid & 63;
    int wv = tid >> 6;                // wave id, 0..3
    const float* row = x + (size_t)r * IN;
#pragma unroll
    for (int it = 0; it < 4; ++it) {
        int b = it * 1024;
        float v[4], t[4], s[4];
#pragma unroll
        for (int e = 0; e < 4; ++e) {
            int c = b + e * 256 + tid;
            v[e] = row[c];
            t[e] = thr[c];
            s[e] = sgn[c];
        }
#pragma unroll
        for (int e = 0; e < 4; ++e) {
            u64 m = __ballot((v[e] - t[e]) * s[e] > 0.f);
            if (lane == 0) xbits[(size_t)r * KW + it * 16 + e * 4 + wv] = m;
        }
    }
}

// ---------------- Kernel 4: binarize weight rows + scale ----------------
__global__ __launch_bounds__(256) void binw(
    const float* __restrict__ w, u64* __restrict__ wbits, float* __restrict__ scale) {
    __shared__ double red[4];
    __shared__ double bcast;
    int o = blockIdx.x;
    int tid = threadIdx.x;
    int lane = tid & 63;
    int wv = tid >> 6;
    const float* row = w + (size_t)o * IN;

    // pass 1: row mean (float4, order-free)
    const float4* row4 = (const float4*)row;
    float part = 0.f;
#pragma unroll
    for (int it = 0; it < IN / 1024; ++it) {
        float4 v = row4[it * 256 + tid];
        part += (v.x + v.y) + (v.z + v.w);
    }
    double d = (double)part;
    for (int off = 32; off > 0; off >>= 1) d += __shfl_down(d, off, 64);
    if (lane == 0) red[wv] = d;
    __syncthreads();
    if (tid == 0) bcast = (red[0] + red[1] + red[2] + red[3]) / (double)IN;
    __syncthreads();
    float mean = (float)bcast;

    // pass 2: sign bits + L1 scale of clipped centered weights
    float absacc = 0.f;
#pragma unroll
    for (int it = 0; it < IN / 256; ++it) {
        float wc = row[it * 256 + tid] - mean;
        u64 mask = __ballot(wc > 0.f);
        if (lane == 0) wbits[(size_t)o * KW + it * 4 + wv] = mask;
        absacc += fminf(fabsf(wc), 1.0f);
    }
    double da = (double)absacc;
    for (int off = 32; off > 0; off >>= 1) da += __shfl_down(da, off, 64);
    if (lane == 0) red[wv] = da;
    __syncthreads();
    if (tid == 0) bcast = (red[0] + red[1] + red[2] + red[3]) / (double)IN;
    __syncthreads();
    if (tid == 0) scale[o] = (float)bcast;
}

// ---------------- Kernel 5: binary GEMM (xnor-popcount) ----------------
// 128x128 tile per block, 256 threads, 8x8 micro-tile (interleaved by 16).
// LSTR=18 (even): ds_read_b128 16B-aligned; read conflicts 2-way (free).
// k-loop fully unrolled -> LDS reads use immediate offsets, zero per-k addr VALU.
#define BK 16              // u64 words per K-chunk (1024 bits)
#define LSTR 18            // padded LDS stride in u64
__global__ __launch_bounds__(256, 4) void bgemm(
    const u64* __restrict__ xbits, const u64* __restrict__ wbits,
    const float* __restrict__ scale, const float* __restrict__ bias,
    float* __restrict__ out) {
    __shared__ u64 xs[128 * LSTR];
    __shared__ u64 wsm[128 * LSTR];

    int tid = threadIdx.x;
    int tx = tid & 15;
    int ty = tid >> 4;
    int colBase = blockIdx.x * 128;
    int rowBase = blockIdx.y * 128;

    int acc[8][8];
#pragma unroll
    for (int i = 0; i < 8; ++i)
#pragma unroll
        for (int j = 0; j < 8; ++j) acc[i][j] = 0;

    // LDS row base pointers (kc-invariant)
    const u64* xrow[8];
    const u64* wrow[8];
#pragma unroll
    for (int i = 0; i < 8; ++i) xrow[i] = &xs[(ty + 16 * i) * LSTR];
#pragma unroll
    for (int j = 0; j < 8; ++j) wrow[j] = &wsm[(tx + 16 * j) * LSTR];

    int rs = tid >> 4;        // staging row within li-group
    int wd = tid & 15;        // staging word

    for (int kc = 0; kc < KW / BK; ++kc) {
        const u64* xg = xbits + (size_t)rowBase * KW + kc * BK;
        const u64* wg = wbits + (size_t)colBase * KW + kc * BK;
#pragma unroll
        for (int li = 0; li < 8; ++li) {
            int r = rs + li * 16;
            xs[r * LSTR + wd] = xg[(size_t)r * KW + wd];
            wsm[r * LSTR + wd] = wg[(size_t)r * KW + wd];
        }
        __syncthreads();

#pragma unroll
        for (int k = 0; k < BK; k += 2) {
            ulonglong2 xv[8], wv[8];
#pragma unroll
            for (int i = 0; i < 8; ++i) xv[i] = *(const ulonglong2*)(xrow[i] + k);
#pragma unroll
            for (int j = 0; j < 8; ++j) wv[j] = *(const ulonglong2*)(wrow[j] + k);
#pragma unroll
            for (int i = 0; i < 8; ++i)
#pragma unroll
                for (int j = 0; j < 8; ++j) {
                    int t = acc[i][j];
                    t = (int)__popcll(xv[i].x ^ wv[j].x) + t;
                    t = (int)__popcll(xv[i].y ^ wv[j].y) + t;
                    acc[i][j] = t;
                }
        }
        __syncthreads();
    }

    // epilogue: dot = IN - 2*mismatches; y = relu((dot + bias) * scale)
    float sc[8], bs[8];
#pragma unroll
    for (int j = 0; j < 8; ++j) {
        int c = colBase + tx + 16 * j;
        sc[j] = scale[c];
        bs[j] = bias[c];
    }
#pragma unroll
    for (int i = 0; i < 8; ++i) {
        int r = rowBase + ty + 16 * i;
        float* orow = out + (size_t)r * OUT;
#pragma unroll
        for (int j = 0; j < 8; ++j) {
            int c = colBase + tx + 16 * j;
            float dot = (float)(IN - 2 * acc[i][j]);
            float y = (dot + bs[j]) * sc[j];
            orow[c] = y > 0.f ? y : 0.f;
        }
    }
}

extern "C" void kernel_launch(void* const* d_in, const int* in_sizes, int n_in,
                              void* d_out, int out_size, void* d_ws, size_t ws_size,
                              hipStream_t stream) {
    const float* x = (const float*)d_in[0];
    const float* gamma = (const float*)d_in[1];
    const float* beta = (const float*)d_in[2];
    const float* weight = (const float*)d_in[3];
    const float* bias = (const float*)d_in[4];
    float* out = (float*)d_out;

    char* w = (char*)d_ws;
    float* thr = (float*)(w);                      // 16KB
    float* sgn = (float*)(w + (1 << 14));          // 16KB
    float* scale = (float*)(w + (2 << 14));        // 16KB
    float* P1 = (float*)(w + (1 << 16));           // 1MB
    float* P2 = (float*)(w + (1 << 16) + (1 << 20));
    u64* xbits = (u64*)(w + (1 << 16) + (2 << 20));       // 4MB
    u64* wbits = xbits + (size_t)BATCH * KW;              // 2MB

    colstat_partial<<<dim3(IN / 1024, NCHUNKS), 256, 0, stream>>>(x, P1, P2);
    colstat_final<<<dim3(IN / 256), 256, 0, stream>>>(P1, P2, gamma, beta, thr, sgn);
    binx<<<dim3(BATCH), 256, 0, stream>>>(x, thr, sgn, xbits);
    binw<<<dim3(OUT), 256, 0, stream>>>(weight, wbits, scale);
    bgemm<<<dim3(OUT / 128, BATCH / 128), 256, 0, stream>>>(xbits, wbits, scale, bias, out);
}

// Round 3
// 925.616 us; speedup vs baseline: 1.9974x; 1.9974x over previous
//
#include <hip/hip_runtime.h>
#include <stdint.h>

#define BATCH 8192
#define IN 4096
#define OUT 4096
#define EPS 1e-4f
#define KW 64              // u64 words per row (4096 bits)
#define RCHUNK 64          // rows per partial-sum block
#define NCHUNKS (BATCH / RCHUNK)   // 128

typedef unsigned long long u64;

// ---------------- Kernel 1: partial column sums (S1, S2), float4 ----------------
__global__ __launch_bounds__(256) void colstat_partial(
    const float* __restrict__ x, float* __restrict__ P1, float* __restrict__ P2) {
    int c4 = blockIdx.x * 256 + threadIdx.x;      // float4 column group
    int r0 = blockIdx.y * RCHUNK;
    float4 s1 = make_float4(0.f, 0.f, 0.f, 0.f);
    float4 s2 = make_float4(0.f, 0.f, 0.f, 0.f);
    const float4* p = (const float4*)x + (size_t)r0 * (IN / 4) + c4;
#pragma unroll 4
    for (int r = 0; r < RCHUNK; ++r) {
        float4 v = p[(size_t)r * (IN / 4)];
        s1.x += v.x; s1.y += v.y; s1.z += v.z; s1.w += v.w;
        s2.x += v.x * v.x; s2.y += v.y * v.y; s2.z += v.z * v.z; s2.w += v.w * v.w;
    }
    ((float4*)P1)[blockIdx.y * (IN / 4) + c4] = s1;
    ((float4*)P2)[blockIdx.y * (IN / 4) + c4] = s2;
}

// ---------------- Kernel 2: finalize -> threshold + sign ----------------
// xn>0  <=>  (x - thr)*sgn > 0, thr = mu - beta/a, a = rstd*gamma
__global__ __launch_bounds__(256) void colstat_final(
    const float* __restrict__ P1, const float* __restrict__ P2,
    const float* __restrict__ gamma, const float* __restrict__ beta,
    float* __restrict__ thr, float* __restrict__ sgn) {
    int col = blockIdx.x * 256 + threadIdx.x;
    double s1 = 0.0, s2 = 0.0;
#pragma unroll 8
    for (int c = 0; c < NCHUNKS; ++c) {
        s1 += (double)P1[c * IN + col];
        s2 += (double)P2[c * IN + col];
    }
    double m = s1 / (double)BATCH;
    double var = s2 / (double)BATCH - m * m;
    float a = (float)(1.0 / sqrt(var + (double)EPS)) * gamma[col];
    thr[col] = (float)m - beta[col] / a;
    sgn[col] = (a >= 0.f) ? 1.f : -1.f;
}

// ---------------- Kernel 3: binarize + bit-pack x ----------------
__global__ __launch_bounds__(256) void binx(
    const float* __restrict__ x, const float* __restrict__ thr,
    const float* __restrict__ sgn, u64* __restrict__ xbits) {
    int r = blockIdx.x;
    int tid = threadIdx.x;
    int lane = tid & 63;
    int wv = tid >> 6;                // wave id, 0..3
    const float* row = x + (size_t)r * IN;
#pragma unroll
    for (int it = 0; it < 4; ++it) {
        int b = it * 1024;
        float v[4], t[4], s[4];
#pragma unroll
        for (int e = 0; e < 4; ++e) {
            int c = b + e * 256 + tid;
            v[e] = row[c];
            t[e] = thr[c];
            s[e] = sgn[c];
        }
#pragma unroll
        for (int e = 0; e < 4; ++e) {
            u64 m = __ballot((v[e] - t[e]) * s[e] > 0.f);
            if (lane == 0) xbits[(size_t)r * KW + it * 16 + e * 4 + wv] = m;
        }
    }
}

// ---------------- Kernel 4: binarize weight rows + scale ----------------
__global__ __launch_bounds__(256) void binw(
    const float* __restrict__ w, u64* __restrict__ wbits, float* __restrict__ scale) {
    __shared__ double red[4];
    __shared__ double bcast;
    int o = blockIdx.x;
    int tid = threadIdx.x;
    int lane = tid & 63;
    int wv = tid >> 6;
    const float* row = w + (size_t)o * IN;

    // pass 1: row mean (float4, order-free)
    const float4* row4 = (const float4*)row;
    float part = 0.f;
#pragma unroll
    for (int it = 0; it < IN / 1024; ++it) {
        float4 v = row4[it * 256 + tid];
        part += (v.x + v.y) + (v.z + v.w);
    }
    double d = (double)part;
    for (int off = 32; off > 0; off >>= 1) d += __shfl_down(d, off, 64);
    if (lane == 0) red[wv] = d;
    __syncthreads();
    if (tid == 0) bcast = (red[0] + red[1] + red[2] + red[3]) / (double)IN;
    __syncthreads();
    float mean = (float)bcast;

    // pass 2: sign bits + L1 scale of clipped centered weights (rows L1-hot)
    float absacc = 0.f;
#pragma unroll
    for (int it = 0; it < IN / 256; ++it) {
        float wc = row[it * 256 + tid] - mean;
        u64 mask = __ballot(wc > 0.f);
        if (lane == 0) wbits[(size_t)o * KW + it * 4 + wv] = mask;
        absacc += fminf(fabsf(wc), 1.0f);
    }
    double da = (double)absacc;
    for (int off = 32; off > 0; off >>= 1) da += __shfl_down(da, off, 64);
    if (lane == 0) red[wv] = da;
    __syncthreads();
    if (tid == 0) bcast = (red[0] + red[1] + red[2] + red[3]) / (double)IN;
    __syncthreads();
    if (tid == 0) scale[o] = (float)bcast;
}

// ---------------- Kernel 5: binary GEMM (xnor-popcount) ----------------
// 128x128 tile per block, 256 threads, 8x8 micro-tile (interleaved by 16).
// LSTR=18 (even): ds_read_b128 16B-aligned; read conflicts 2-way (free).
// k-loop fully unrolled -> LDS reads get immediate offsets from one base.
// __launch_bounds__(256,2): VGPR cap 256 -- do NOT tighten; (256,4) spilled
// acc to scratch (R2: 5.2GB HBM scratch traffic, 5x regression).
#define BK 16              // u64 words per K-chunk (1024 bits)
#define LSTR 18            // padded LDS stride in u64
__global__ __launch_bounds__(256, 2) void bgemm(
    const u64* __restrict__ xbits, const u64* __restrict__ wbits,
    const float* __restrict__ scale, const float* __restrict__ bias,
    float* __restrict__ out) {
    __shared__ u64 xs[128 * LSTR];
    __shared__ u64 wsm[128 * LSTR];

    int tid = threadIdx.x;
    int tx = tid & 15;
    int ty = tid >> 4;
    int colBase = blockIdx.x * 128;
    int rowBase = blockIdx.y * 128;

    int acc[8][8];
#pragma unroll
    for (int i = 0; i < 8; ++i)
#pragma unroll
        for (int j = 0; j < 8; ++j) acc[i][j] = 0;

    int xb = ty * LSTR;       // LDS base index for A reads
    int wb = tx * LSTR;       // LDS base index for B reads
    int srow = tid >> 3;      // staging row 0..31
    int sw = (tid & 7) * 2;   // staging word pair

    for (int kc = 0; kc < KW / BK; ++kc) {
        const u64* xg = xbits + (size_t)rowBase * KW + kc * BK;
        const u64* wg = wbits + (size_t)colBase * KW + kc * BK;
#pragma unroll
        for (int li = 0; li < 4; ++li) {
            int r = srow + li * 32;
            *(ulonglong2*)&xs[r * LSTR + sw] = *(const ulonglong2*)&xg[(size_t)r * KW + sw];
            *(ulonglong2*)&wsm[r * LSTR + sw] = *(const ulonglong2*)&wg[(size_t)r * KW + sw];
        }
        __syncthreads();

#pragma unroll
        for (int k = 0; k < BK; k += 2) {
            ulonglong2 xv[8], wv[8];
#pragma unroll
            for (int i = 0; i < 8; ++i) xv[i] = *(const ulonglong2*)&xs[xb + 16 * i * LSTR + k];
#pragma unroll
            for (int j = 0; j < 8; ++j) wv[j] = *(const ulonglong2*)&wsm[wb + 16 * j * LSTR + k];
#pragma unroll
            for (int i = 0; i < 8; ++i)
#pragma unroll
                for (int j = 0; j < 8; ++j) {
                    int t = acc[i][j];
                    t = (int)__popcll(xv[i].x ^ wv[j].x) + t;
                    t = (int)__popcll(xv[i].y ^ wv[j].y) + t;
                    acc[i][j] = t;
                }
        }
        __syncthreads();
    }

    // epilogue: dot = IN - 2*mismatches; y = relu((dot + bias) * scale)
    float sc[8], bs[8];
#pragma unroll
    for (int j = 0; j < 8; ++j) {
        int c = colBase + tx + 16 * j;
        sc[j] = scale[c];
        bs[j] = bias[c];
    }
#pragma unroll
    for (int i = 0; i < 8; ++i) {
        int r = rowBase + ty + 16 * i;
        float* orow = out + (size_t)r * OUT;
#pragma unroll
        for (int j = 0; j < 8; ++j) {
            int c = colBase + tx + 16 * j;
            float dot = (float)(IN - 2 * acc[i][j]);
            float y = (dot + bs[j]) * sc[j];
            orow[c] = y > 0.f ? y : 0.f;
        }
    }
}

extern "C" void kernel_launch(void* const* d_in, const int* in_sizes, int n_in,
                              void* d_out, int out_size, void* d_ws, size_t ws_size,
                              hipStream_t stream) {
    const float* x = (const float*)d_in[0];
    const float* gamma = (const float*)d_in[1];
    const float* beta = (const float*)d_in[2];
    const float* weight = (const float*)d_in[3];
    const float* bias = (const float*)d_in[4];
    float* out = (float*)d_out;

    char* w = (char*)d_ws;
    float* thr = (float*)(w);                      // 16KB
    float* sgn = (float*)(w + (1 << 14));          // 16KB
    float* scale = (float*)(w + (2 << 14));        // 16KB
    float* P1 = (float*)(w + (1 << 20));           // 2MB (128 x 4096 f32)
    float* P2 = (float*)(w + (3 << 20));           // 2MB
    u64* xbits = (u64*)(w + (5 << 20));            // 4MB
    u64* wbits = xbits + (size_t)BATCH * KW;       // 2MB

    colstat_partial<<<dim3(IN / 1024, NCHUNKS), 256, 0, stream>>>(x, P1, P2);
    colstat_final<<<dim3(IN / 256), 256, 0, stream>>>(P1, P2, gamma, beta, thr, sgn);
    binx<<<dim3(BATCH), 256, 0, stream>>>(x, thr, sgn, xbits);
    binw<<<dim3(OUT), 256, 0, stream>>>(weight, wbits, scale);
    bgemm<<<dim3(OUT / 128, BATCH / 128), 256, 0, stream>>>(xbits, wbits, scale, bias, out);
}